// Round 3
// baseline (261.659 us; speedup 1.0000x reference)
//
#include <hip/hip_runtime.h>
#include <hip/hip_bf16.h>

// AttentionBlock: B=16, N=2048, D=128, fp32 in/out.
// K1 (256 blk x 256 thr): all-3-W LDS staging once/block, 128 rows/block,
//     bf16 MFMA projections eq/ek/evT + mask precompute.
// K2 (256 blk x 512 thr): flash attention, 8 waves x 16 q-rows, online softmax.

#define NEGBIG -4294967296.0f            // float32(-2^32+1) rounds to -2^32
#define SCALE  0.08838834764831845f      // 1/sqrt(128)

typedef __bf16 bf16x8 __attribute__((ext_vector_type(8)));
typedef __bf16 bf16x4 __attribute__((ext_vector_type(4)));
typedef float  f32x4  __attribute__((ext_vector_type(4)));

// ---------------- Kernel 1: projections + masks ----------------
template<bool TP>
static __device__ __forceinline__ void do_proj(
    const __bf16* Wl, const float* __restrict__ bias,
    const bf16x8 a[2][4], __bf16* __restrict__ dst, __bf16* stage,
    int tid, int wave, int col, int quad, int rowbase)
{
    #pragma unroll
    for (int g = 0; g < 2; ++g) {
        f32x4 acc[8];
        #pragma unroll
        for (int ct = 0; ct < 8; ++ct) { f32x4 z = {0.f, 0.f, 0.f, 0.f}; acc[ct] = z; }
        #pragma unroll
        for (int f = 0; f < 4; ++f) {
            #pragma unroll
            for (int ct = 0; ct < 8; ++ct) {
                bf16x8 bfr = *(const bf16x8*)&Wl[(ct * 16 + col) * 136 + f * 32 + quad * 8];
                acc[ct] = __builtin_amdgcn_mfma_f32_16x16x32_bf16(a[g][f], bfr, acc[ct], 0, 0, 0);
            }
        }
        // C-layout: row(out-row) = quad*4+r, col(out-d) = lane&15 (ct*16+col)
        #pragma unroll
        for (int ct = 0; ct < 8; ++ct) {
            float bv = bias[ct * 16 + col];
            #pragma unroll
            for (int r = 0; r < 4; ++r) {
                float v = acc[ct][r] + bv;
                int rr = g * 64 + wave * 16 + quad * 4 + r;
                if (TP) stage[(ct * 16 + col) * 136 + rr] = (__bf16)v;   // [d][m]
                else    stage[rr * 136 + ct * 16 + col] = (__bf16)v;     // [row][d]
            }
        }
    }
    __syncthreads();
    if (!TP) {
        // 128 rows x 256B: thread -> (row = tid>>1, half-row of 128B = 8x uint4)
        int r = tid >> 1, seg = (tid & 1) * 64;
        uint4* g4 = (uint4*)(dst + (size_t)(rowbase + r) * 128 + seg);
        const uint4* s4 = (const uint4*)&stage[r * 136 + seg];
        #pragma unroll
        for (int i = 0; i < 8; ++i) g4[i] = s4[i];
    } else {
        // evT [b][d][2048]; this block owns a 128-wide m-slice
        int d = tid >> 1, seg = (tid & 1) * 64;
        int bb = rowbase >> 11, mb = rowbase & 2047;
        uint4* g4 = (uint4*)(dst + (size_t)bb * 128 * 2048 + (size_t)d * 2048 + mb + seg);
        const uint4* s4 = (const uint4*)&stage[d * 136 + seg];
        #pragma unroll
        for (int i = 0; i < 8; ++i) g4[i] = s4[i];
    }
    __syncthreads();
}

__global__ __launch_bounds__(256) void proj_kernel(
    const float* __restrict__ Q, const float* __restrict__ K,
    const int* __restrict__ PM,
    const float* __restrict__ Wq, const float* __restrict__ Bq,
    const float* __restrict__ Wk, const float* __restrict__ Bk,
    const float* __restrict__ Wv, const float* __restrict__ Bv,
    __bf16* __restrict__ eqb, __bf16* __restrict__ ekb, __bf16* __restrict__ evT,
    float* __restrict__ ksel, float* __restrict__ kovr, float* __restrict__ qpad)
{
    __shared__ __bf16 Wl[3][128 * 136];     // 3 x 34.8 KB
    __shared__ __bf16 stage[128 * 136];     // 34.8 KB  (total ~139 KB)
    const int tid  = threadIdx.x;
    const int wave = tid >> 6, lane = tid & 63;
    const int col  = lane & 15, quad = lane >> 4;
    const int rowbase = blockIdx.x * 128;

    // A-frags (fp32 -> bf16) + exact fp32 row sums, two 64-row groups
    bf16x8 aq[2][4], ak[2][4];
    float qs[2], kss[2];
    #pragma unroll
    for (int g = 0; g < 2; ++g) {
        const int myrow = rowbase + g * 64 + wave * 16 + col;
        qs[g] = 0.f; kss[g] = 0.f;
        #pragma unroll
        for (int f = 0; f < 4; ++f) {
            const float* pq = Q + (size_t)myrow * 128 + f * 32 + quad * 8;
            const float* pk = K + (size_t)myrow * 128 + f * 32 + quad * 8;
            float4 q0 = *(const float4*)pq, q1 = *(const float4*)(pq + 4);
            float4 k0 = *(const float4*)pk, k1 = *(const float4*)(pk + 4);
            float qv[8] = {q0.x, q0.y, q0.z, q0.w, q1.x, q1.y, q1.z, q1.w};
            float kv[8] = {k0.x, k0.y, k0.z, k0.w, k1.x, k1.y, k1.z, k1.w};
            #pragma unroll
            for (int j = 0; j < 8; ++j) {
                qs[g] += qv[j]; kss[g] += kv[j];
                aq[g][f][j] = (__bf16)qv[j];
                ak[g][f][j] = (__bf16)kv[j];
            }
        }
    }

    // Stage all three W (coalesced float4 -> packed bf16x4 ds_write_b64)
    #pragma unroll
    for (int w = 0; w < 3; ++w) {
        const float* Wp = (w == 0) ? Wq : (w == 1) ? Wk : Wv;
        for (int i = tid * 4; i < 128 * 128; i += 1024) {
            float4 v = *(const float4*)&Wp[i];
            bf16x4 t = {(__bf16)v.x, (__bf16)v.y, (__bf16)v.z, (__bf16)v.w};
            *(bf16x4*)&Wl[w][(i >> 7) * 136 + (i & 127)] = t;
        }
    }

    // masks (full-row sums: reduce the 4 quads sharing lane&15)
    #pragma unroll
    for (int g = 0; g < 2; ++g) {
        float a = qs[g], b = kss[g];
        a += __shfl_xor(a, 16); a += __shfl_xor(a, 32);
        b += __shfl_xor(b, 16); b += __shfl_xor(b, 32);
        if (quad == 0) {
            const int myrow = rowbase + g * 64 + wave * 16 + col;
            qpad[myrow] = (a != 0.f) ? 1.f : 0.f;
            int pmv = PM[myrow];
            ksel[myrow] = (pmv != 0) ? 1.f : 0.f;
            kovr[myrow] = (pmv != 0) ? 0.f : ((b == 0.f) ? NEGBIG : 0.f);
        }
    }
    __syncthreads();

    do_proj<false>(Wl[0], Bq, aq, eqb, stage, tid, wave, col, quad, rowbase);
    do_proj<false>(Wl[1], Bk, ak, ekb, stage, tid, wave, col, quad, rowbase);
    do_proj<true >(Wl[2], Bv, ak, evT, stage, tid, wave, col, quad, rowbase);
}

// ---------------- Kernel 2: flash attention ----------------
// 8 waves x 16 q-rows = 128-row q-tile per block; key tiles of 64.
// Grid MUST be 256: 16 batches x 16 q-tiles.
__global__ __launch_bounds__(512, 1) void attn_kernel(
    const __bf16* __restrict__ eqb, const __bf16* __restrict__ ekb,
    const __bf16* __restrict__ evT,
    const float* __restrict__ ksel, const float* __restrict__ kovr,
    const float* __restrict__ qpad,
    const float* __restrict__ Q, float* __restrict__ out)
{
    __shared__ __bf16 ekt[64 * 136];     // [m][d] stride 136 (17.4 KB)
    __shared__ __bf16 evt[128 * 72];     // [d][m] stride 72  (18.4 KB)
    __shared__ __bf16 pt[8][16 * 72];    // per-wave P strip [q][m] (18.4 KB)

    const int tid  = threadIdx.x;
    const int wave = tid >> 6, lane = tid & 63;
    const int col  = lane & 15, quad = lane >> 4;
    const int b  = blockIdx.x & 15;            // 16 batches
    const int qt = blockIdx.x >> 4;            // 16 q-tiles of 128 rows
    const int rowg0 = b * 2048 + qt * 128 + wave * 16;

    bf16x8 aqf[4];
    #pragma unroll
    for (int f = 0; f < 4; ++f)
        aqf[f] = *(const bf16x8*)&eqb[(size_t)(rowg0 + col) * 128 + f * 32 + quad * 8];

    f32x4 o[8];
    float mold[4], lsum[4];
    #pragma unroll
    for (int dt = 0; dt < 8; ++dt) { f32x4 z = {0.f, 0.f, 0.f, 0.f}; o[dt] = z; }
    #pragma unroll
    for (int r = 0; r < 4; ++r) { mold[r] = -1e30f; lsum[r] = 0.f; }

    for (int it = 0; it < 32; ++it) {
        const int mbase = it * 64;
        // stage K tile (64x128) and V^T tile (128x64): 4 uint4 per thread
        const uint4* gk = (const uint4*)(ekb + (size_t)(b * 2048 + mbase) * 128);
        #pragma unroll
        for (int i = 0; i < 2; ++i) {
            int j = tid + i * 512;
            *(uint4*)&ekt[(j >> 4) * 136 + (j & 15) * 8] = gk[j];
        }
        const __bf16* gv = evT + (size_t)b * 128 * 2048 + mbase;
        #pragma unroll
        for (int i = 0; i < 2; ++i) {
            int j = tid + i * 512;
            *(uint4*)&evt[(j >> 3) * 72 + (j & 7) * 8] =
                *(const uint4*)(gv + (size_t)(j >> 3) * 2048 + (j & 7) * 8);
        }
        __syncthreads();

        // S = eq @ ek^T  (C-layout: q = quad*4+r, m-col = lane&15)
        f32x4 s[4];
        #pragma unroll
        for (int mt = 0; mt < 4; ++mt) { f32x4 z = {0.f, 0.f, 0.f, 0.f}; s[mt] = z; }
        #pragma unroll
        for (int f = 0; f < 4; ++f) {
            #pragma unroll
            for (int mt = 0; mt < 4; ++mt) {
                bf16x8 bfr = *(const bf16x8*)&ekt[(mt * 16 + col) * 136 + f * 32 + quad * 8];
                s[mt] = __builtin_amdgcn_mfma_f32_16x16x32_bf16(aqf[f], bfr, s[mt], 0, 0, 0);
            }
        }

        // mask + scale: s = coefs*scale*sel + ovr
        float msel[4], movr[4], qpd[4];
        #pragma unroll
        for (int mt = 0; mt < 4; ++mt) {
            int m = b * 2048 + mbase + mt * 16 + col;
            msel[mt] = ksel[m] * SCALE;
            movr[mt] = kovr[m];
            qpd[mt]  = qpad[m];
        }
        #pragma unroll
        for (int mt = 0; mt < 4; ++mt)
            #pragma unroll
            for (int r = 0; r < 4; ++r)
                s[mt][r] = s[mt][r] * msel[mt] + movr[mt];

        // online softmax (in-quad shfl_xor 1,2,4,8)
        #pragma unroll
        for (int r = 0; r < 4; ++r) {
            float v = fmaxf(fmaxf(s[0][r], s[1][r]), fmaxf(s[2][r], s[3][r]));
            v = fmaxf(v, __shfl_xor(v, 1));
            v = fmaxf(v, __shfl_xor(v, 2));
            v = fmaxf(v, __shfl_xor(v, 4));
            v = fmaxf(v, __shfl_xor(v, 8));
            float mnew  = fmaxf(mold[r], v);
            float alpha = __expf(mold[r] - mnew);
            mold[r] = mnew;
            float ts = 0.f;
            #pragma unroll
            for (int mt = 0; mt < 4; ++mt) {
                float e = __expf(s[mt][r] - mnew);
                s[mt][r] = e;
                ts += e;
            }
            ts += __shfl_xor(ts, 1);
            ts += __shfl_xor(ts, 2);
            ts += __shfl_xor(ts, 4);
            ts += __shfl_xor(ts, 8);
            lsum[r] = lsum[r] * alpha + ts;
            #pragma unroll
            for (int dt = 0; dt < 8; ++dt) o[dt][r] *= alpha;
        }
        // P (with faithful q_pad-along-key-axis multiply) -> LDS in A-operand order
        #pragma unroll
        for (int mt = 0; mt < 4; ++mt)
            #pragma unroll
            for (int r = 0; r < 4; ++r)
                pt[wave][(quad * 4 + r) * 72 + mt * 16 + col] =
                    (__bf16)(s[mt][r] * qpd[mt]);

        // O += P @ ev (wave-private pt strip: no barrier needed, same-wave RAW)
        #pragma unroll
        for (int ks = 0; ks < 2; ++ks) {
            bf16x8 pa = *(const bf16x8*)&pt[wave][col * 72 + ks * 32 + quad * 8];
            #pragma unroll
            for (int dt = 0; dt < 8; ++dt) {
                bf16x8 bv = *(const bf16x8*)&evt[(dt * 16 + col) * 72 + ks * 32 + quad * 8];
                o[dt] = __builtin_amdgcn_mfma_f32_16x16x32_bf16(pa, bv, o[dt], 0, 0, 0);
            }
        }
        __syncthreads();
    }

    // epilogue: normalize by l, add residual queries (fp32), store fp32
    float inv[4];
    #pragma unroll
    for (int r = 0; r < 4; ++r) inv[r] = 1.f / lsum[r];
    #pragma unroll
    for (int dt = 0; dt < 8; ++dt)
        #pragma unroll
        for (int r = 0; r < 4; ++r) {
            size_t idx = (size_t)(rowg0 + quad * 4 + r) * 128 + dt * 16 + col;
            out[idx] = o[dt][r] * inv[r] + Q[idx];
        }
}

extern "C" void kernel_launch(void* const* d_in, const int* in_sizes, int n_in,
                              void* d_out, int out_size, void* d_ws, size_t ws_size,
                              hipStream_t stream)
{
    const float* Q  = (const float*)d_in[0];
    const float* K  = (const float*)d_in[1];
    const int*   PM = (const int*)d_in[2];
    const float* Wq = (const float*)d_in[3];
    const float* Bq = (const float*)d_in[4];
    const float* Wk = (const float*)d_in[5];
    const float* Bk = (const float*)d_in[6];
    const float* Wv = (const float*)d_in[7];
    const float* Bv = (const float*)d_in[8];
    float* out = (float*)d_out;

    const size_t SZE = (size_t)16 * 2048 * 128;     // 4,194,304 elements
    __bf16* eqb = (__bf16*)d_ws;                    // 8 MB
    __bf16* ekb = eqb + SZE;                        // 8 MB
    __bf16* evT = ekb + SZE;                        // 8 MB, layout [B][D][N]
    float* ksel = (float*)(evT + SZE);              // 128 KB each
    float* kovr = ksel + 16 * 2048;
    float* qpad = kovr + 16 * 2048;

    proj_kernel<<<256, 256, 0, stream>>>(Q, K, PM, Wq, Bq, Wk, Bk, Wv, Bv,
                                         eqb, ekb, evT, ksel, kovr, qpad);
    attn_kernel<<<256, 512, 0, stream>>>(eqb, ekb, evT, ksel, kovr, qpad, Q, out);
}